// Round 1
// baseline (48.762 us; speedup 1.0000x reference)
//
#include <hip/hip_runtime.h>
#include <math.h>

#define NPIX (512*1024)   // H*W = 524288
#define NB   8
#define KBINS 16
#define CBINS 4
#define NACC 84           // 64 p_cl + 16 p_c + 4 p_l
#define BLOCKS 512
#define TPB 256

__device__ __forceinline__ float fexp2(float x){ return __builtin_amdgcn_exp2f(x); }
__device__ __forceinline__ float frcp (float x){ return __builtin_amdgcn_rcpf(x); }

// Kernel 1: per-block partial accumulation of p_cl (16x4), p_c (16), p_l (4).
__launch_bounds__(TPB, 2)
__global__ void nid_partial(const float* __restrict__ cam,
                            const float* __restrict__ lab,
                            float* __restrict__ ws)
{
    constexpr float L2E = 1.4426950408889634f;
    const int tid    = blockIdx.x * TPB + threadIdx.x;
    const int stride = BLOCKS * TPB;

    float acc[KBINS][CBINS];
    float accC[KBINS];
    float accL[CBINS];
    #pragma unroll
    for (int k = 0; k < KBINS; k++) {
        accC[k] = 0.f;
        #pragma unroll
        for (int c = 0; c < CBINS; c++) acc[k][c] = 0.f;
    }
    #pragma unroll
    for (int c = 0; c < CBINS; c++) accL[c] = 0.f;

    for (int n = tid; n < NPIX; n += stride) {
        // Edge-sigmoid sums over the batch. P_c[k] = Sc[k]-Sc[k+1], P_l[c] = Sl[c]-Sl[c+1].
        float Sc[KBINS + 1];
        float Sl[CBINS + 1];
        #pragma unroll
        for (int j = 0; j <= KBINS; j++) Sc[j] = 0.f;
        #pragma unroll
        for (int j = 0; j <= CBINS; j++) Sl[j] = 0.f;

        #pragma unroll
        for (int b = 0; b < NB; b++) {
            // camera gray: (c0+c1+c2)/3; fold /3 and *200*log2e into one scale
            const float* cb = cam + (size_t)(b * 3) * NPIX + n;
            float c0 = cb[0];
            float c1 = cb[NPIX];
            float c2 = cb[2 * NPIX];
            float t = (c0 + c1 + c2) * (200.0f / 3.0f * L2E);
            // sigmoid edge j at cam-value j/16: sig((g - j/16)*200) = 1/(1+2^(Cj - t))
            #pragma unroll
            for (int j = 0; j <= KBINS; j++) {
                float e = fexp2((float)j * (12.5f * L2E) - t);
                Sc[j] += frcp(1.0f + e);
            }

            // soft-argmax over 4 label channels, beta=500
            const float* lb = lab + (size_t)(b * 4) * NPIX + n;
            float a0 = lb[0], a1 = lb[NPIX], a2 = lb[2 * NPIX], a3 = lb[3 * NPIX];
            float m  = fmaxf(fmaxf(a0, a1), fmaxf(a2, a3));
            float mk = m * (500.0f * L2E);
            float e0 = fexp2(fmaf(a0, 500.0f * L2E, -mk));
            float e1 = fexp2(fmaf(a1, 500.0f * L2E, -mk));
            float e2 = fexp2(fmaf(a2, 500.0f * L2E, -mk));
            float e3 = fexp2(fmaf(a3, 500.0f * L2E, -mk));
            float s  = e0 + e1 + e2 + e3;
            float am = fmaf(3.0f, e3, fmaf(2.0f, e2, e1)) * frcp(s + 1e-12f);

            // label edge sigmoids at (j-0.5), scale 1000
            float u = am * (1000.0f * L2E);
            #pragma unroll
            for (int j = 0; j <= CBINS; j++) {
                float e = fexp2(((float)j - 0.5f) * (1000.0f * L2E) - u);
                Sl[j] += frcp(1.0f + e);
            }
        }

        float Pc[KBINS], Pl[CBINS];
        #pragma unroll
        for (int k = 0; k < KBINS; k++) Pc[k] = Sc[k] - Sc[k + 1];
        #pragma unroll
        for (int c = 0; c < CBINS; c++) Pl[c] = Sl[c] - Sl[c + 1];

        #pragma unroll
        for (int k = 0; k < KBINS; k++) {
            accC[k] += Pc[k];
            #pragma unroll
            for (int c = 0; c < CBINS; c++) acc[k][c] = fmaf(Pc[k], Pl[c], acc[k][c]);
        }
        #pragma unroll
        for (int c = 0; c < CBINS; c++) accL[c] += Pl[c];
    }

    // Block reduction: 3-step xor butterfly (sums of 8 lanes) -> LDS -> 84 threads finish.
    __shared__ float red[32][NACC];
    const int lane = threadIdx.x & 63;
    const int wv   = threadIdx.x >> 6;

    auto redstore = [&](int idx, float v) {
        v += __shfl_xor(v, 1);
        v += __shfl_xor(v, 2);
        v += __shfl_xor(v, 4);
        if ((lane & 7) == 0) red[wv * 8 + (lane >> 3)][idx] = v;
    };

    #pragma unroll
    for (int k = 0; k < KBINS; k++) {
        #pragma unroll
        for (int c = 0; c < CBINS; c++) redstore(k * 4 + c, acc[k][c]);
    }
    #pragma unroll
    for (int k = 0; k < KBINS; k++) redstore(64 + k, accC[k]);
    #pragma unroll
    for (int c = 0; c < CBINS; c++) redstore(80 + c, accL[c]);

    __syncthreads();
    if (threadIdx.x < NACC) {
        float s = 0.f;
        #pragma unroll
        for (int g = 0; g < 32; g++) s += red[g][threadIdx.x];
        ws[(size_t)blockIdx.x * NACC + threadIdx.x] = s;
    }
}

// Kernel 2: reduce 512 block-partials in double, compute NID scalar.
__global__ void nid_final(const float* __restrict__ ws, float* __restrict__ out)
{
    __shared__ double partA[8][NACC];
    __shared__ double sm[NACC];
    __shared__ double tot[3];
    const int t = threadIdx.x;  // block of 768

    if (t < 8 * NACC) {
        int v = t % NACC;
        int g = t / NACC;
        double s = 0.0;
        #pragma unroll 8
        for (int i = g * 64; i < g * 64 + 64; i++)
            s += (double)ws[(size_t)i * NACC + v];
        partA[g][v] = s;
    }
    __syncthreads();
    if (t < NACC) {
        double s = 0.0;
        #pragma unroll
        for (int g = 0; g < 8; g++) s += partA[g][t];
        sm[t] = s;
    }
    __syncthreads();
    if (t == 0) {
        double a = 0, b = 0, c = 0;
        for (int v = 0; v < 64; v++) a += sm[v];
        for (int k = 0; k < 16; k++) b += sm[64 + k];
        for (int v = 0; v < 4; v++)  c += sm[80 + v];
        tot[0] = a; tot[1] = b; tot[2] = c;
    }
    __syncthreads();
    if (t < 64) {
        int k = t >> 2, c = t & 3;
        double pcl = sm[t] / tot[0];
        double po  = (sm[64 + k] / tot[1]) * (sm[80 + c] / tot[2]);
        double lp  = log(pcl + 1e-7);
        double lo  = log(po + 1e-7);
        double dI  = pcl * (lp - lo);
        double dH  = -pcl * lp;
        #pragma unroll
        for (int m = 1; m < 64; m <<= 1) {
            dI += __shfl_xor(dI, m);
            dH += __shfl_xor(dH, m);
        }
        if (t == 0) out[0] = (float)((1.0 - dI / dH - 0.95) * 20.0);
    }
}

extern "C" void kernel_launch(void* const* d_in, const int* in_sizes, int n_in,
                              void* d_out, int out_size, void* d_ws, size_t ws_size,
                              hipStream_t stream)
{
    const float* cam = (const float*)d_in[0];
    const float* lab = (const float*)d_in[1];
    float* ws = (float*)d_ws;

    hipLaunchKernelGGL(nid_partial, dim3(BLOCKS), dim3(TPB), 0, stream, cam, lab, ws);
    hipLaunchKernelGGL(nid_final, dim3(1), dim3(768), 0, stream, ws, (float*)d_out);
}

// Round 2
// 48.335 us; speedup vs baseline: 1.0088x; 1.0088x over previous
//
#include <hip/hip_runtime.h>
#include <math.h>

#define NPIX (512*1024)   // H*W = 524288
#define NB   8
#define KBINS 16
#define CBINS 4
#define NACC 68           // 64 p_cl + 4 p_l  (p_c derived as row-sums of p_cl)
#define BLOCKS 1024
#define TPB 256

__device__ __forceinline__ float fexp2(float x){ return __builtin_amdgcn_exp2f(x); }
__device__ __forceinline__ float frcp (float x){ return __builtin_amdgcn_rcpf(x); }

// Kernel 1: each thread owns 2 consecutive pixels (float2 loads), accumulates
// p_cl (16x4) + p_l (4) over 8 batches, block-reduces 68 stats to ws.
__launch_bounds__(TPB, 4)
__global__ void nid_partial(const float* __restrict__ cam,
                            const float* __restrict__ lab,
                            float* __restrict__ ws)
{
    constexpr float L2E  = 1.4426950408889634f;
    constexpr float CSC  = 200.0f / 3.0f * L2E;   // gray-sum -> exp2-domain scale
    constexpr float ESTP = 12.5f * L2E;           // camera edge step in exp2 domain
    constexpr float LSC  = 1000.0f * L2E;         // label edge scale

    const int tid = blockIdx.x * TPB + threadIdx.x;   // 262144 threads
    const int n0  = tid * 2;                          // pixel pair (n0, n0+1)

    float Sc0[KBINS + 1], Sc1[KBINS + 1];
    float pl0[CBINS], pl1[CBINS];
    #pragma unroll
    for (int j = 0; j <= KBINS; j++) { Sc0[j] = 0.f; Sc1[j] = 0.f; }
    #pragma unroll
    for (int c = 0; c < CBINS; c++) { pl0[c] = 0.f; pl1[c] = 0.f; }

    #pragma unroll
    for (int b = 0; b < NB; b++) {
        // ---- camera: gray = (r+g+b)/3, 17 edge sigmoids per pixel ----
        const float* cbase = cam + (size_t)(b * 3) * NPIX + n0;
        float2 c0 = *(const float2*)(cbase);
        float2 c1 = *(const float2*)(cbase + NPIX);
        float2 c2 = *(const float2*)(cbase + 2 * NPIX);
        float t0 = (c0.x + c1.x + c2.x) * CSC;
        float t1 = (c0.y + c1.y + c2.y) * CSC;
        #pragma unroll
        for (int j = 0; j <= KBINS; j++) {
            Sc0[j] += frcp(1.0f + fexp2((float)j * ESTP - t0));
            Sc1[j] += frcp(1.0f + fexp2((float)j * ESTP - t1));
        }

        // ---- label: soft-argmax (beta=500) then single live edge sigmoid ----
        const float* lbase = lab + (size_t)(b * 4) * NPIX + n0;
        float2 a0 = *(const float2*)(lbase);
        float2 a1 = *(const float2*)(lbase + NPIX);
        float2 a2 = *(const float2*)(lbase + 2 * NPIX);
        float2 a3 = *(const float2*)(lbase + 3 * NPIX);

        #pragma unroll
        for (int px = 0; px < 2; px++) {
            float x0 = px ? a0.y : a0.x;
            float x1 = px ? a1.y : a1.x;
            float x2 = px ? a2.y : a2.x;
            float x3 = px ? a3.y : a3.x;
            float m  = fmaxf(fmaxf(x0, x1), fmaxf(x2, x3));
            float mk = m * (500.0f * L2E);
            float e0 = fexp2(fmaf(x0, 500.0f * L2E, -mk));
            float e1 = fexp2(fmaf(x1, 500.0f * L2E, -mk));
            float e2 = fexp2(fmaf(x2, 500.0f * L2E, -mk));
            float e3 = fexp2(fmaf(x3, 500.0f * L2E, -mk));
            float am = fmaf(3.0f, e3, fmaf(2.0f, e2, e1)) * frcp(e0 + e1 + e2 + e3 + 1e-12f);

            // edges at j-0.5 (j=0..4), scale 1000: only the nearest edge is
            // non-saturated in fp32 (spacing 1.0 >> transition width ~0.09).
            float fj = rintf(am + 0.5f);                       // nearest edge index
            float v  = frcp(1.0f + fexp2((fj - 0.5f - am) * LSC));  // sigma at that edge
            float* pl = px ? pl1 : pl0;
            #pragma unroll
            for (int c = 0; c < CBINS; c++) {
                // Pl[c] = 1-v if c==fj-1, v if c==fj, else 0
                float add = (fj == (float)(c + 1)) ? (1.0f - v)
                          : (fj == (float)c)       ? v : 0.0f;
                pl[c] += add;
            }
        }
    }

    // ---- per-thread outer products ----
    float acc[NACC];
    #pragma unroll
    for (int k = 0; k < KBINS; k++) {
        float Pc0 = Sc0[k] - Sc0[k + 1];
        float Pc1 = Sc1[k] - Sc1[k + 1];
        #pragma unroll
        for (int c = 0; c < CBINS; c++)
            acc[k * 4 + c] = fmaf(Pc0, pl0[c], Pc1 * pl1[c]);
    }
    #pragma unroll
    for (int c = 0; c < CBINS; c++) acc[64 + c] = pl0[c] + pl1[c];

    // ---- block reduction: 3-step butterfly (8-lane sums) -> LDS -> 68 threads ----
    __shared__ float red[32][NACC];
    const int lane = threadIdx.x & 63;
    const int wv   = threadIdx.x >> 6;

    #pragma unroll
    for (int i = 0; i < NACC; i++) {
        float v = acc[i];
        v += __shfl_xor(v, 1);
        v += __shfl_xor(v, 2);
        v += __shfl_xor(v, 4);
        if ((lane & 7) == 0) red[wv * 8 + (lane >> 3)][i] = v;
    }

    __syncthreads();
    if (threadIdx.x < NACC) {
        float s = 0.f;
        #pragma unroll
        for (int g = 0; g < 32; g++) s += red[g][threadIdx.x];
        ws[(size_t)blockIdx.x * NACC + threadIdx.x] = s;
    }
}

// Kernel 2: reduce 1024 block-partials in double, compute NID scalar.
__global__ void nid_final(const float* __restrict__ ws, float* __restrict__ out)
{
    __shared__ double partA[8][NACC];
    __shared__ double sm[NACC];
    __shared__ double tots[2];
    const int t = threadIdx.x;  // block of 544

    if (t < 8 * NACC) {
        int v = t % NACC;
        int g = t / NACC;
        double s = 0.0;
        #pragma unroll 8
        for (int i = g * 128; i < g * 128 + 128; i++)
            s += (double)ws[(size_t)i * NACC + v];
        partA[g][v] = s;
    }
    __syncthreads();
    if (t < NACC) {
        double s = 0.0;
        #pragma unroll
        for (int g = 0; g < 8; g++) s += partA[g][t];
        sm[t] = s;
    }
    __syncthreads();
    if (t == 0) {
        double a = 0, bb = 0;
        for (int v = 0; v < 64; v++) a += sm[v];
        for (int c = 0; c < 4; c++)  bb += sm[64 + c];
        tots[0] = a; tots[1] = bb;
    }
    __syncthreads();
    if (t < 64) {
        int k = t >> 2, c = t & 3;
        double pcl = sm[t] / tots[0];
        double pc  = (sm[k * 4] + sm[k * 4 + 1] + sm[k * 4 + 2] + sm[k * 4 + 3]) / tots[0];
        double pl  = sm[64 + c] / tots[1];
        double lp  = log(pcl + 1e-7);
        double lo  = log(pc * pl + 1e-7);
        double dI  = pcl * (lp - lo);
        double dH  = -pcl * lp;
        #pragma unroll
        for (int m = 1; m < 64; m <<= 1) {
            dI += __shfl_xor(dI, m);
            dH += __shfl_xor(dH, m);
        }
        if (t == 0) out[0] = (float)((1.0 - dI / dH - 0.95) * 20.0);
    }
}

extern "C" void kernel_launch(void* const* d_in, const int* in_sizes, int n_in,
                              void* d_out, int out_size, void* d_ws, size_t ws_size,
                              hipStream_t stream)
{
    const float* cam = (const float*)d_in[0];
    const float* lab = (const float*)d_in[1];
    float* ws = (float*)d_ws;

    hipLaunchKernelGGL(nid_partial, dim3(BLOCKS), dim3(TPB), 0, stream, cam, lab, ws);
    hipLaunchKernelGGL(nid_final, dim3(1), dim3(544), 0, stream, ws, (float*)d_out);
}